// Round 7
// baseline (285.322 us; speedup 1.0000x reference)
//
#include <hip/hip_runtime.h>
#include <math.h>

#define NF 40
#define FS 401
#define AST 424            // A row stride (f16), 848B, 16B-aligned rows
#define PSTRIDE 160
#define BB 8
#define LL 160000
#define PADL 256
#define LST 161024         // PADL + LL + 768 pad; multiple of 256
#define TOUT 1000
#define NTILE 512          // conv positions per block (4 waves x 128)
#define NCHUNKC 313        // 313*512 = 160256 >= 160000
#define ROWCH 121          // slab chunk stride per row; 121 % 8 == 1
#define ROWST (ROWCH*8)    // 968 f16 per row
#define EROW 520           // e-LDS row stride (f16); 260 dwords ≡ 4 mod 32 -> e-store conflict-free; rows 16B-aligned
#define WL2 432            // shifted window row stride (f32): 401 taps + head shift + zero pad
#define NCONVB 5032        // BB*LST/256 exactly

typedef __attribute__((ext_vector_type(8))) _Float16 half8v;
typedef __attribute__((ext_vector_type(4))) _Float16 half4v;
typedef __attribute__((ext_vector_type(2))) _Float16 half2v;
typedef __attribute__((ext_vector_type(4))) float float4v;
typedef _Float16 f16;

__device__ __forceinline__ float sigm(float x) { return 1.0f / (1.0f + __expf(-x)); }
__device__ __forceinline__ float tanh_fast(float x) { return 1.0f - 2.0f / (__expf(2.0f * x) + 1.0f); }

// ---------- prep (single dispatch): x->f16 padded, Gabor filters, shifted f32 pool windows ----------
__global__ __launch_bounds__(256) void prep_all(
    const float* __restrict__ x, const float* __restrict__ cf_,
    const float* __restrict__ bw_, const float* __restrict__ pw_,
    f16* __restrict__ xb, f16* __restrict__ Ag, float* __restrict__ Wg4f)
{
    int blk = blockIdx.x;
    if (blk < NCONVB) {
        int i = blk * 256 + threadIdx.x;
        int b = i / LST, o = i % LST;
        float v = 0.0f;
        if (o >= PADL && o < PADL + LL) v = x[b * LL + (o - PADL)];
        xb[i] = (f16)v;
        return;
    }
    if (blk < NCONVB + 80) {
        const float PI_F = 3.14159265358979323846f;
        int row = blk - NCONVB;         // 0..79
        int f = row >> 1, comp = row & 1;
        float Z = sqrtf(2.0f * logf(2.0f)) / PI_F;
        float cf = fminf(fmaxf(cf_[f], 0.0f), PI_F);
        float bw = fminf(fmaxf(bw_[f], 4.0f * Z), 401.0f * Z);
        float denom = 1.0f / (sqrtf(2.0f * PI_F) * bw);
        float inv2 = 1.0f / (2.0f * bw * bw);
        for (int k = threadIdx.x; k < AST; k += 256) {
            float v = 0.0f;
            if (k < FS) {
                float t = (float)(k - 200);
                float g = denom * expf(-(t * t) * inv2);
                float sv, cv;
                sincosf(cf * t, &sv, &cv);
                v = comp ? g * sv : g * cv;
            }
            Ag[row * AST + k] = (f16)v;
        }
        return;
    }
    // shifted f32 pool windows: Wg4f[f][r][p] = win(p - 2r), r in 0..3, zero OOB
    int f = blk - (NCONVB + 80);    // 0..39
    float pw = fminf(fmaxf(pw_[f], 2.0f / 401.0f), 0.5f);
    float invpw = 1.0f / pw;
    for (int idx = threadIdx.x; idx < 4 * WL2; idx += 256) {
        int r = idx / WL2, p = idx - r * WL2;
        int k = p - 2 * r;
        float w = 0.0f;
        if (k >= 0 && k < FS) {
            float ttv = (float)k * (1.0f / 400.0f) - 0.5f;
            float u = ttv * invpw;
            w = expf(-0.5f * u * u);
        }
        Wg4f[(f * 4 + r) * WL2 + p] = w;
    }
}

// ---------- conv via MFMA + fused Gaussian pooling -> per-tile partials (plain stores) ----------
__global__ __launch_bounds__(256, 2) void conv_pool(
    const f16* __restrict__ xb,    // padded [BB][LST]
    const f16* __restrict__ Ag,    // [80][AST]
    const float* __restrict__ Wg4f,// [40][4][WL2] shifted pool windows (f32)
    float* __restrict__ Pp)        // [BB][TOUT][NF][2] pool partials, slot = chunk&1
{
    // overlay: slab (8*ROWST f16 = 15488 B) during K-loop, e-tile (40*EROW f16 = 41600 B) after
    __shared__ __align__(16) unsigned char smem[40 * EROW * 2];
    f16* slab = (f16*)smem;
    f16* eL   = (f16*)smem;

    int chunk = blockIdx.x;
    int bi = blockIdx.y;
    int p0 = chunk * NTILE;
    int pbase = PADL + p0 - 200;              // ≡ 0 (mod 8)
    const f16* xs = xb + (size_t)bi * LST;
    int tid = threadIdx.x;

    // build 8-shifted-row slab: 8 rows x 120 chunks (columns 0..959 covered)
    for (int sc = tid; sc < 8 * 120; sc += 256) {
        int r = sc / 120, m = sc - r * 120;
        int s0 = pbase + 8 * m + (r & ~1);
        const uint* gp = (const uint*)(xs + s0);
        uint v0 = gp[0], v1 = gp[1], v2 = gp[2], v3 = gp[3], v4 = gp[4];
        if (r & 1) {
            v0 = __builtin_amdgcn_alignbyte(v1, v0, 2);
            v1 = __builtin_amdgcn_alignbyte(v2, v1, 2);
            v2 = __builtin_amdgcn_alignbyte(v3, v2, 2);
            v3 = __builtin_amdgcn_alignbyte(v4, v3, 2);
        }
        *(uint4*)(&slab[r * ROWST + 8 * m]) = make_uint4(v0, v1, v2, v3);
    }
    __syncthreads();

    int wv = tid >> 6, lane = tid & 63, q = lane >> 4, l15 = lane & 15;

    float4v acc[5][8];
#pragma unroll
    for (int t = 0; t < 5; ++t)
#pragma unroll
        for (int s = 0; s < 8; ++s)
            acc[t][s] = (float4v){0.f, 0.f, 0.f, 0.f};

    const f16* aP[5];
    const f16* bPtr[10];
#pragma unroll
    for (int t = 0; t < 5; ++t) aP[t] = Ag + (16 * t + l15) * AST + 8 * q;
#pragma unroll
    for (int s = 0; s < 10; ++s) {
        int pos = 128 * wv + 16 * s + l15;    // up to 543
        bPtr[s] = slab + (pos & 7) * ROWST + 8 * ((pos >> 3) + q);
    }

    half8v bf[8];
#pragma unroll
    for (int s = 0; s < 8; ++s) bf[s] = *(const half8v*)(bPtr[s]);

#pragma unroll
    for (int kk = 0; kk < 13; ++kk) {
        int k = 32 * kk;
        half8v af[5];
#pragma unroll
        for (int t = 0; t < 5; ++t) af[t] = *(const half8v*)(aP[t] + k);
        half8v nb0, nb1;
        if (kk < 12) {
            nb0 = *(const half8v*)(bPtr[8] + k);
            nb1 = *(const half8v*)(bPtr[9] + k);
        }
#pragma unroll
        for (int t = 0; t < 5; ++t)
#pragma unroll
            for (int s = 0; s < 8; ++s)
                acc[t][s] = __builtin_amdgcn_mfma_f32_16x16x32_f16(af[t], bf[s], acc[t][s], 0, 0, 0);
        if (kk < 12) {
#pragma unroll
            for (int s = 0; s < 6; ++s) bf[s] = bf[s + 2];
            bf[6] = nb0; bf[7] = nb1;
        }
    }

    __syncthreads();   // slab dead; eL overlays

    // energies -> LDS e-tile [40][EROW]; zero beyond LL (reference zero-pads y)
#pragma unroll
    for (int t = 0; t < 5; ++t) {
        int f0 = 8 * t + 2 * q;
#pragma unroll
        for (int s = 0; s < 8; ++s) {
            float4v a = acc[t][s];
            int pl = 128 * wv + 16 * s + l15;
            bool ok = (p0 + pl) < LL;
            eL[f0 * EROW + pl] = ok ? (f16)(a.x * a.x + a.y * a.y) : (f16)0.f;
            eL[(f0 + 1) * EROW + pl] = ok ? (f16)(a.z * a.z + a.w * a.w) : (f16)0.f;
        }
    }
    // zero pad columns 512..519 (block j=64 reads)
    for (int i = tid; i < 40 * 8; i += 256) {
        int r = i >> 3, cc = 512 + (i & 7);
        eL[r * EROW + cc] = (f16)0.f;
    }
    __syncthreads();

    // ---- fused pooling: 16-lane group per (tau,f); 8 taps/lane/iter, masked, 8 indep chains ----
    // frame tau window covers positions [tau*160-200, tau*160+200]
    int tau_lo = (p0 - 41) / 160;             // == max(0, ceil((p0-200)/160)) for p0 >= 0
    if (tau_lo < 0) tau_lo = 0;
    int tau_hi = (p0 + 711) / 160;
    if (tau_hi > TOUT - 1) tau_hi = TOUT - 1;
    int npr = (tau_hi - tau_lo + 1) * 40;     // <= 240
    int slot = chunk & 1;
    int gid = tid >> 4;                       // 16 groups of 16 lanes
    int lg = tid & 15;

    for (int pr = gid; pr < npr; pr += 16) {
        int ta = pr / 40;
        int f = pr - ta * 40;
        int tau = tau_lo + ta;
        int b = tau * 160 - 200 - p0;         // even, in [-200, 510]
        int bc = b > 0 ? b : 0;
        int j0 = bc >> 3;                     // first e-block with valid taps
        int r = (b & 7) >> 1;                 // shifted-window copy (b even -> 2r == (b&7))
        int pw0 = 8 * j0 - b + 2 * r;         // >= 0, multiple of 8 -> f32 base 32B aligned
        int jlast = (b + 400) >> 3;           // last e-block with a valid tap (k<=400)
        if (jlast > 64) jlast = 64;
        const f16* ebase = eL + f * EROW;
        const float* wbase = Wg4f + ((f * 4 + r) * WL2) + pw0;
        float4v pac0 = {0.f, 0.f, 0.f, 0.f};
        float4v pac1 = {0.f, 0.f, 0.f, 0.f};
#pragma unroll
        for (int i = 0; i < 4; ++i) {
            int j = j0 + 16 * i + lg;
            bool act = (j <= jlast);          // per-lane mask
            int jc = act ? j : j0;            // safe dummy when inactive
            // bounds (act): e idx 8*jc+7 <= 519 < EROW; w idx pw0+8*(jc-j0)+7 <= 413 < WL2
            half8v e8 = *(const half8v*)(ebase + 8 * jc);
            const float* wp = wbase + 8 * (jc - j0);
            float4v w0 = *(const float4v*)(wp);
            float4v w1 = *(const float4v*)(wp + 4);
            if (act) {
                pac0.x = fmaf((float)e8[0], w0.x, pac0.x);
                pac0.y = fmaf((float)e8[1], w0.y, pac0.y);
                pac0.z = fmaf((float)e8[2], w0.z, pac0.z);
                pac0.w = fmaf((float)e8[3], w0.w, pac0.w);
                pac1.x = fmaf((float)e8[4], w1.x, pac1.x);
                pac1.y = fmaf((float)e8[5], w1.y, pac1.y);
                pac1.z = fmaf((float)e8[6], w1.z, pac1.z);
                pac1.w = fmaf((float)e8[7], w1.w, pac1.w);
            }
        }
        float pa = ((pac0.x + pac0.y) + (pac0.z + pac0.w))
                 + ((pac1.x + pac1.y) + (pac1.z + pac1.w));
        pa += __shfl_xor(pa, 1, 16);
        pa += __shfl_xor(pa, 2, 16);
        pa += __shfl_xor(pa, 4, 16);
        pa += __shfl_xor(pa, 8, 16);
        if (lg == 0)
            Pp[(((size_t)bi * TOUT + tau) * NF + f) * 2 + slot] = pa;
    }
}

// ---------- combine partials -> X, then PCEN smoother M via wave-per-bin decayed scan ----------
__global__ __launch_bounds__(256) void pcen_scan_kernel(
    const float* __restrict__ Pp, float* __restrict__ X, float* __restrict__ M)
{
    int wid = (blockIdx.x * 256 + threadIdx.x) >> 6;
    int lane = threadIdx.x & 63;
    if (wid >= BB * NF) return;
    const float a1 = 0.96f;
    const float a2 = a1 * a1;
    const float a4 = a2 * a2;
    const float a8 = a4 * a4;
    const float a16 = a8 * a8;
    const float a32 = a16 * a16;
    const float ss = 0.04f;
    float al1 = powf(a1, (float)(lane + 1));
    float carry = 0.0f;
    int bi = wid / NF, f = wid - bi * NF;
    const float* pbase = Pp + (size_t)bi * TOUT * NF * 2 + f * 2;
    float* xrow = X + (size_t)wid * TOUT;
    float* mrow = M + (size_t)wid * TOUT;

    for (int c = 0; c < TOUT; c += 64) {
        int t = c + lane;
        float v = 0.0f;
        if (t < TOUT) {
            int s = t * 160 - 200;
            int cl = (s > 0) ? (s >> 9) : 0;          // first contributing tile
            int ch = (s + 400) >> 9;                  // last contributing tile
            if (ch > NCHUNKC - 1) ch = NCHUNKC - 1;
            v = pbase[(size_t)t * NF * 2 + (cl & 1)];
            if (ch > cl) v += pbase[(size_t)t * NF * 2 + ((cl & 1) ^ 1)];
            xrow[t] = v;
        }
        float y = ss * v;
        float u;
        u = __shfl_up(y, 1, 64);  if (lane >= 1)  y = fmaf(a1, u, y);
        u = __shfl_up(y, 2, 64);  if (lane >= 2)  y = fmaf(a2, u, y);
        u = __shfl_up(y, 4, 64);  if (lane >= 4)  y = fmaf(a4, u, y);
        u = __shfl_up(y, 8, 64);  if (lane >= 8)  y = fmaf(a8, u, y);
        u = __shfl_up(y, 16, 64); if (lane >= 16) y = fmaf(a16, u, y);
        u = __shfl_up(y, 32, 64); if (lane >= 32) y = fmaf(a32, u, y);
        y = fmaf(al1, carry, y);
        carry = __shfl(y, 63, 64);
        if (t < TOUT) mrow[t] = y;
    }
}

// ---------- GRU controller + PCEN via MFMA (C-layout gates); 8 instance-groups per block ----------
__global__ __launch_bounds__(256) void pcen_ctrl_mfma(
    const float* __restrict__ X, const float* __restrict__ M,
    const float* __restrict__ w_ih, const float* __restrict__ w_hh,
    const float* __restrict__ b_ih, const float* __restrict__ b_hh,
    const float* __restrict__ hw1, const float* __restrict__ hb1,
    const float* __restrict__ hw2, const float* __restrict__ hb2,
    float* __restrict__ out)
{
    __shared__ f16 s_whhA[96 * 40];
    __shared__ f16 s_w1A[32 * 40];
    __shared__ __align__(16) float4 s_A1[32];
    __shared__ __align__(16) float4 s_A2[32];
    __shared__ float s_hb1[32];
    __shared__ float s_hw2[64];
    __shared__ float s_hb2[2];
    __shared__ f16 sh1[4][16 * 40];
    __shared__ f16 sh2[4][16 * 40];
    __shared__ float sxc[4][16], sxp[4][16], smv[4][16];

    int tid = threadIdx.x;
    for (int i = tid; i < 96 * 32; i += 256) {
        int m = i >> 5, k = i & 31;
        s_whhA[m * 40 + k] = (f16)w_hh[i];
    }
    for (int i = tid; i < 32 * 32; i += 256) {
        int m = i >> 5, k = i & 31;
        s_w1A[m * 40 + k] = (f16)hw1[i];
    }
    if (tid < 32) {
        int j = tid;
        s_A1[j] = make_float4(w_ih[j], b_ih[j] + b_hh[j],
                              w_ih[32 + j], b_ih[32 + j] + b_hh[32 + j]);
        s_A2[j] = make_float4(w_ih[64 + j], b_ih[64 + j], b_hh[64 + j], 0.0f);
        s_hb1[j] = hb1[j];
    }
    if (tid < 64) s_hw2[tid] = hw2[tid];
    if (tid < 2)  s_hb2[tid] = hb2[tid];
    __syncthreads();

    int wv = tid >> 6, lane = tid & 63;
    int c = lane & 15, q = lane >> 4;

    for (int rep = 0; rep < 8; ++rep) {
        int instBase = blockIdx.x * 512 + rep * 64 + wv * 16;

        if (lane < 16) {
            int idx = instBase + lane;
            int t = idx % TOUT;
            float xcv = X[idx];
            float xpv = (t == 0) ? xcv : X[idx - 1];
            sxc[wv][lane] = xcv;
            sxp[wv][lane] = xpv;
            smv[wv][lane] = M[idx];
        }
        float xp = sxp[wv][c];
        float xc = sxc[wv][c];
        float mv = smv[wv][c];

        float h1v[8];
#pragma unroll
        for (int jj = 0; jj < 8; ++jj) {
            int j = (jj < 4) ? (4 * q + jj) : (16 + 4 * q + (jj - 4));
            float4 a1 = s_A1[j];
            float4 a2 = s_A2[j];
            float r = sigm(fmaf(xp, a1.x, a1.y));
            float z = sigm(fmaf(xp, a1.z, a1.w));
            float n = tanh_fast(fmaf(xp, a2.x, a2.y) + r * a2.z);
            h1v[jj] = (1.0f - z) * n;
        }

        {
            half4v lo = {(f16)h1v[0], (f16)h1v[1], (f16)h1v[2], (f16)h1v[3]};
            half4v hi = {(f16)h1v[4], (f16)h1v[5], (f16)h1v[6], (f16)h1v[7]};
            *(half4v*)(&sh1[wv][c * 40 + 4 * q]) = lo;
            *(half4v*)(&sh1[wv][c * 40 + 16 + 4 * q]) = hi;
        }

        float4v acc[6];
        {
            half8v bf = *(const half8v*)(&sh1[wv][c * 40 + 8 * q]);
#pragma unroll
            for (int t = 0; t < 6; ++t) {
                half8v af = *(const half8v*)(&s_whhA[(16 * t + c) * 40 + 8 * q]);
                acc[t] = __builtin_amdgcn_mfma_f32_16x16x32_f16(af, bf, (float4v){0.f,0.f,0.f,0.f}, 0, 0, 0);
            }
        }

        float h2v[8];
#pragma unroll
        for (int jj = 0; jj < 8; ++jj) {
            int j = (jj < 4) ? (4 * q + jj) : (16 + 4 * q + (jj - 4));
            int reg = jj & 3;
            float accR = (jj < 4) ? acc[0][reg] : acc[1][reg];
            float accZ = (jj < 4) ? acc[2][reg] : acc[3][reg];
            float accN = (jj < 4) ? acc[4][reg] : acc[5][reg];
            float4 a1 = s_A1[j];
            float4 a2 = s_A2[j];
            float r = sigm(fmaf(xc, a1.x, a1.y) + accR);
            float z = sigm(fmaf(xc, a1.z, a1.w) + accZ);
            float gn = accN + a2.z;
            float n = tanh_fast(fmaf(xc, a2.x, a2.y) + r * gn);
            h2v[jj] = fmaf(z, h1v[jj] - n, n);
        }

        {
            half4v lo = {(f16)h2v[0], (f16)h2v[1], (f16)h2v[2], (f16)h2v[3]};
            half4v hi = {(f16)h2v[4], (f16)h2v[5], (f16)h2v[6], (f16)h2v[7]};
            *(half4v*)(&sh2[wv][c * 40 + 4 * q]) = lo;
            *(half4v*)(&sh2[wv][c * 40 + 16 + 4 * q]) = hi;
        }

        float4v hacc[2];
        {
            half8v bf = *(const half8v*)(&sh2[wv][c * 40 + 8 * q]);
#pragma unroll
            for (int t = 0; t < 2; ++t) {
                half8v af = *(const half8v*)(&s_w1A[(16 * t + c) * 40 + 8 * q]);
                hacc[t] = __builtin_amdgcn_mfma_f32_16x16x32_f16(af, bf, (float4v){0.f,0.f,0.f,0.f}, 0, 0, 0);
            }
        }

        float p0 = 0.f, p1 = 0.f;
#pragma unroll
        for (int jj = 0; jj < 8; ++jj) {
            int i = (jj < 4) ? (4 * q + jj) : (16 + 4 * q + (jj - 4));
            int reg = jj & 3;
            float hv = (jj < 4) ? hacc[0][reg] : hacc[1][reg];
            hv = fmaxf(hv + s_hb1[i], 0.0f);
            p0 = fmaf(hv, s_hw2[i], p0);
            p1 = fmaf(hv, s_hw2[32 + i], p1);
        }
        p0 += __shfl_xor(p0, 16);
        p0 += __shfl_xor(p0, 32);
        p1 += __shfl_xor(p1, 16);
        p1 += __shfl_xor(p1, 32);

        float alpha = sigm(p0 + s_hb2[0]);
        float rr = fmaf(0.8f, sigm(p1 + s_hb2[1]), 0.2f);
        float md = __expf(alpha * __logf(mv + 1e-6f));
        float bse = xc / md + 2.0f;
        float val = __expf(rr * __logf(bse)) - __expf(rr * 0.69314718056f);
        if (lane < 16)
            out[instBase + lane] = val;
    }
}

extern "C" void kernel_launch(void* const* d_in, const int* in_sizes, int n_in,
                              void* d_out, int out_size, void* d_ws, size_t ws_size,
                              hipStream_t stream) {
    const float* x    = (const float*)d_in[0];
    const float* cf   = (const float*)d_in[1];
    const float* bw   = (const float*)d_in[2];
    const float* pw   = (const float*)d_in[3];
    const float* w_ih = (const float*)d_in[4];
    const float* w_hh = (const float*)d_in[5];
    const float* b_ih = (const float*)d_in[6];
    const float* b_hh = (const float*)d_in[7];
    const float* hw1  = (const float*)d_in[8];
    const float* hb1  = (const float*)d_in[9];
    const float* hw2  = (const float*)d_in[10];
    const float* hb2  = (const float*)d_in[11];
    float* out = (float*)d_out;

    // workspace: xb | Ag | Wg4f [40][4][WL2] f32 | Pp [BB][TOUT][NF][2] f32 | X | M  (~8.2 MB)
    f16* xb     = (f16*)d_ws;
    f16* Ag     = xb + (size_t)BB * LST;
    float* Wg4f = (float*)(Ag + (size_t)80 * AST);   // byte ofs 2,644,224 (16B aligned)
    float* Pp   = Wg4f + (size_t)NF * 4 * WL2;
    float* Xf   = Pp + (size_t)BB * TOUT * NF * 2;
    float* Mf   = Xf + (size_t)BB * NF * TOUT;

    prep_all<<<dim3(NCONVB + 80 + 40), dim3(256), 0, stream>>>(
        x, cf, bw, pw, xb, Ag, Wg4f);

    conv_pool<<<dim3(NCHUNKC, BB), dim3(256), 0, stream>>>(xb, Ag, Wg4f, Pp);

    pcen_scan_kernel<<<dim3((BB * NF * 64) / 256), dim3(256), 0, stream>>>(Pp, Xf, Mf);
    pcen_ctrl_mfma<<<dim3((BB * NF * TOUT) / 512), dim3(256), 0, stream>>>(
        Xf, Mf, w_ih, w_hh, b_ih, b_hh, hw1, hb1, hw2, hb2, out);
}

// Round 8
// 267.164 us; speedup vs baseline: 1.0680x; 1.0680x over previous
//
#include <hip/hip_runtime.h>
#include <math.h>

#define NF 40
#define FS 401
#define AST 424            // A row stride (f16), 848B, 16B-aligned rows
#define PSTRIDE 160
#define BB 8
#define LL 160000
#define PADL 256
#define LST 161024         // PADL + LL + 768 pad; multiple of 256
#define TOUT 1000
#define NTILE 512          // conv positions per block (4 waves x 128)
#define NCHUNKC 313        // 313*512 = 160256 >= 160000
#define ROWCH 121          // slab chunk stride per row; 121 % 8 == 1
#define ROWST (ROWCH*8)    // 968 f16 per row
#define EROW 520           // e-LDS row stride (f16); 260 dwords ≡ 4 mod 32 -> e-store conflict-free; rows 16B-aligned
#define WROW 424           // window row stride (f16): 8 front-pad zeros + 401 taps + tail zeros
#define NCONVB 5032        // BB*LST/256 exactly

typedef __attribute__((ext_vector_type(8))) _Float16 half8v;
typedef __attribute__((ext_vector_type(4))) _Float16 half4v;
typedef __attribute__((ext_vector_type(2))) _Float16 half2v;
typedef __attribute__((ext_vector_type(4))) float float4v;
typedef _Float16 f16;

__device__ __forceinline__ float sigm(float x) { return 1.0f / (1.0f + __expf(-x)); }
__device__ __forceinline__ float tanh_fast(float x) { return 1.0f - 2.0f / (__expf(2.0f * x) + 1.0f); }

// ---------- prep (single dispatch): x->f16 padded, Gabor filters, padded f16 pool window ----------
__global__ __launch_bounds__(256) void prep_all(
    const float* __restrict__ x, const float* __restrict__ cf_,
    const float* __restrict__ bw_, const float* __restrict__ pw_,
    f16* __restrict__ xb, f16* __restrict__ Ag, f16* __restrict__ Wf16)
{
    int blk = blockIdx.x;
    if (blk < NCONVB) {
        int i = blk * 256 + threadIdx.x;
        int b = i / LST, o = i % LST;
        float v = 0.0f;
        if (o >= PADL && o < PADL + LL) v = x[b * LL + (o - PADL)];
        xb[i] = (f16)v;
        return;
    }
    if (blk < NCONVB + 80) {
        const float PI_F = 3.14159265358979323846f;
        int row = blk - NCONVB;         // 0..79
        int f = row >> 1, comp = row & 1;
        float Z = sqrtf(2.0f * logf(2.0f)) / PI_F;
        float cf = fminf(fmaxf(cf_[f], 0.0f), PI_F);
        float bw = fminf(fmaxf(bw_[f], 4.0f * Z), 401.0f * Z);
        float denom = 1.0f / (sqrtf(2.0f * PI_F) * bw);
        float inv2 = 1.0f / (2.0f * bw * bw);
        for (int k = threadIdx.x; k < AST; k += 256) {
            float v = 0.0f;
            if (k < FS) {
                float t = (float)(k - 200);
                float g = denom * expf(-(t * t) * inv2);
                float sv, cv;
                sincosf(cf * t, &sv, &cv);
                v = comp ? g * sv : g * cv;
            }
            Ag[row * AST + k] = (f16)v;
        }
        return;
    }
    // padded f16 pool window: Wf16[f][p] = win(p - 8), zero for p-8 outside [0,401)
    int f = blk - (NCONVB + 80);    // 0..39
    float pw = fminf(fmaxf(pw_[f], 2.0f / 401.0f), 0.5f);
    float invpw = 1.0f / pw;
    for (int p = threadIdx.x; p < WROW; p += 256) {
        int k = p - 8;
        float w = 0.0f;
        if (k >= 0 && k < FS) {
            float ttv = (float)k * (1.0f / 400.0f) - 0.5f;
            float u = ttv * invpw;
            w = expf(-0.5f * u * u);
        }
        Wf16[f * WROW + p] = (f16)w;
    }
}

// ---------- conv via MFMA + fused Gaussian pooling (LDS window, two 20-filter passes) ----------
__global__ __launch_bounds__(256, 2) void conv_pool(
    const f16* __restrict__ xb,    // padded [BB][LST]
    const f16* __restrict__ Ag,    // [80][AST]
    const f16* __restrict__ Wf16,  // [40][WROW] padded pool window (f16)
    float* __restrict__ Pp)        // [BB][TOUT][NF][2] pool partials, slot = chunk&1
{
    // overlay: slab (8*ROWST f16 = 15488 B) during K-loop, e-tile (40*EROW f16 = 41600 B) after
    __shared__ __align__(16) unsigned char smem[40 * EROW * 2];
    __shared__ __align__(16) f16 wt[20 * WROW];   // 16960 B window stage (20 rows per pass)
    f16* slab = (f16*)smem;
    f16* eL   = (f16*)smem;

    int chunk = blockIdx.x;
    int bi = blockIdx.y;
    int p0 = chunk * NTILE;
    int pbase = PADL + p0 - 200;              // ≡ 0 (mod 8)
    const f16* xs = xb + (size_t)bi * LST;
    int tid = threadIdx.x;

    // build 8-shifted-row slab: 8 rows x 120 chunks (columns 0..959 covered)
    for (int sc = tid; sc < 8 * 120; sc += 256) {
        int r = sc / 120, m = sc - r * 120;
        int s0 = pbase + 8 * m + (r & ~1);
        const uint* gp = (const uint*)(xs + s0);
        uint v0 = gp[0], v1 = gp[1], v2 = gp[2], v3 = gp[3], v4 = gp[4];
        if (r & 1) {
            v0 = __builtin_amdgcn_alignbyte(v1, v0, 2);
            v1 = __builtin_amdgcn_alignbyte(v2, v1, 2);
            v2 = __builtin_amdgcn_alignbyte(v3, v2, 2);
            v3 = __builtin_amdgcn_alignbyte(v4, v3, 2);
        }
        *(uint4*)(&slab[r * ROWST + 8 * m]) = make_uint4(v0, v1, v2, v3);
    }
    __syncthreads();

    int wv = tid >> 6, lane = tid & 63, q = lane >> 4, l15 = lane & 15;

    float4v acc[5][8];
#pragma unroll
    for (int t = 0; t < 5; ++t)
#pragma unroll
        for (int s = 0; s < 8; ++s)
            acc[t][s] = (float4v){0.f, 0.f, 0.f, 0.f};

    const f16* aP[5];
    const f16* bPtr[10];
#pragma unroll
    for (int t = 0; t < 5; ++t) aP[t] = Ag + (16 * t + l15) * AST + 8 * q;
#pragma unroll
    for (int s = 0; s < 10; ++s) {
        int pos = 128 * wv + 16 * s + l15;    // up to 543
        bPtr[s] = slab + (pos & 7) * ROWST + 8 * ((pos >> 3) + q);
    }

    half8v bf[8];
#pragma unroll
    for (int s = 0; s < 8; ++s) bf[s] = *(const half8v*)(bPtr[s]);

#pragma unroll
    for (int kk = 0; kk < 13; ++kk) {
        int k = 32 * kk;
        half8v af[5];
#pragma unroll
        for (int t = 0; t < 5; ++t) af[t] = *(const half8v*)(aP[t] + k);
        half8v nb0, nb1;
        if (kk < 12) {
            nb0 = *(const half8v*)(bPtr[8] + k);
            nb1 = *(const half8v*)(bPtr[9] + k);
        }
#pragma unroll
        for (int t = 0; t < 5; ++t)
#pragma unroll
            for (int s = 0; s < 8; ++s)
                acc[t][s] = __builtin_amdgcn_mfma_f32_16x16x32_f16(af[t], bf[s], acc[t][s], 0, 0, 0);
        if (kk < 12) {
#pragma unroll
            for (int s = 0; s < 6; ++s) bf[s] = bf[s + 2];
            bf[6] = nb0; bf[7] = nb1;
        }
    }

    __syncthreads();   // slab dead; eL overlays

    // energies -> LDS e-tile [40][EROW]; zero beyond LL (reference zero-pads y)
#pragma unroll
    for (int t = 0; t < 5; ++t) {
        int f0 = 8 * t + 2 * q;
#pragma unroll
        for (int s = 0; s < 8; ++s) {
            float4v a = acc[t][s];
            int pl = 128 * wv + 16 * s + l15;
            bool ok = (p0 + pl) < LL;
            eL[f0 * EROW + pl] = ok ? (f16)(a.x * a.x + a.y * a.y) : (f16)0.f;
            eL[(f0 + 1) * EROW + pl] = ok ? (f16)(a.z * a.z + a.w * a.w) : (f16)0.f;
        }
    }
    // zero pad columns 512..519 (block j=64 reads)
    for (int i = tid; i < 40 * 8; i += 256) {
        int r = i >> 3, cc = 512 + (i & 7);
        eL[r * EROW + cc] = (f16)0.f;
    }

    // ---- fused pooling: LDS window, two 20-filter passes; 16-lane group per (tau,f) ----
    // frame tau window covers positions [tau*160-200, tau*160+200]
    int tau_lo = (p0 - 41) / 160;             // == max(0, ceil((p0-200)/160)) for p0 >= 0
    if (tau_lo < 0) tau_lo = 0;
    int tau_hi = (p0 + 711) / 160;
    if (tau_hi > TOUT - 1) tau_hi = TOUT - 1;
    int ntau = tau_hi - tau_lo + 1;           // <= 6
    int b0 = tau_lo * 160 - 200 - p0;
    int slot = chunk & 1;
    int gid = tid >> 4;                       // 16 groups of 16 lanes
    int lg = tid & 15;

    for (int half = 0; half < 2; ++half) {
        // stage 20 window rows (16960 B) from global into wt (coalesced b128)
        {
            const half8v* src = (const half8v*)(Wf16 + 20 * WROW * half);
            half8v* dst = (half8v*)wt;
            for (int i = tid; i < 20 * WROW / 8; i += 256)   // 1060
                dst[i] = src[i];
        }
        __syncthreads();   // also covers e-store on first pass

        int nprh = ntau * 20;
        int fi = gid;      // gid <= 15 < 20 -> ta starts 0
        int ta = 0;
        for (int pr = gid; pr < nprh; pr += 16) {
            int f = 20 * half + fi;
            int tau = tau_lo + ta;
            int b = b0 + 160 * ta;            // even, in [-200, 510]
            int bc = b > 0 ? b : 0;
            int j0 = bc >> 3;                 // first e-block with valid taps
            int jlast = (b + 400) >> 3;       // last e-block with a valid tap
            if (jlast > 64) jlast = 64;
            const f16* ebase = eL + f * EROW;
            int wbaseIdx = fi * WROW + 8 - b; // + 8*jc gives tap k = 8jc-b at pad-8 layout
            float4v pac0 = {0.f, 0.f, 0.f, 0.f};
            float4v pac1 = {0.f, 0.f, 0.f, 0.f};
#pragma unroll
            for (int i = 0; i < 4; ++i) {
                int j = j0 + 16 * i + lg;
                bool act = (j <= jlast);      // per-lane mask
                int jc = act ? j : j0;        // safe dummy when inactive
                // bounds (act): e idx 8*jc+7 <= 519 < EROW; w idx in [fi*WROW+1, fi*WROW+415]
                half8v e8 = *(const half8v*)(ebase + 8 * jc);
                const f16* wp = wt + wbaseIdx + 8 * jc;   // 4B-aligned (b even)
                half2v w0 = *(const half2v*)(wp);
                half2v w1 = *(const half2v*)(wp + 2);
                half2v w2 = *(const half2v*)(wp + 4);
                half2v w3 = *(const half2v*)(wp + 6);
                if (act) {
                    pac0.x = fmaf((float)e8[0], (float)w0[0], pac0.x);
                    pac0.y = fmaf((float)e8[1], (float)w0[1], pac0.y);
                    pac0.z = fmaf((float)e8[2], (float)w1[0], pac0.z);
                    pac0.w = fmaf((float)e8[3], (float)w1[1], pac0.w);
                    pac1.x = fmaf((float)e8[4], (float)w2[0], pac1.x);
                    pac1.y = fmaf((float)e8[5], (float)w2[1], pac1.y);
                    pac1.z = fmaf((float)e8[6], (float)w3[0], pac1.z);
                    pac1.w = fmaf((float)e8[7], (float)w3[1], pac1.w);
                }
            }
            float pa = ((pac0.x + pac0.y) + (pac0.z + pac0.w))
                     + ((pac1.x + pac1.y) + (pac1.z + pac1.w));
            pa += __shfl_xor(pa, 1, 16);
            pa += __shfl_xor(pa, 2, 16);
            pa += __shfl_xor(pa, 4, 16);
            pa += __shfl_xor(pa, 8, 16);
            if (lg == 0)
                Pp[(((size_t)bi * TOUT + tau) * NF + f) * 2 + slot] = pa;
            fi += 16; if (fi >= 20) { fi -= 20; ++ta; }
        }
        __syncthreads();   // wt reads done before next pass restages
    }
}

// ---------- combine partials -> X, then PCEN smoother M via wave-per-bin decayed scan ----------
__global__ __launch_bounds__(256) void pcen_scan_kernel(
    const float* __restrict__ Pp, float* __restrict__ X, float* __restrict__ M)
{
    int wid = (blockIdx.x * 256 + threadIdx.x) >> 6;
    int lane = threadIdx.x & 63;
    if (wid >= BB * NF) return;
    const float a1 = 0.96f;
    const float a2 = a1 * a1;
    const float a4 = a2 * a2;
    const float a8 = a4 * a4;
    const float a16 = a8 * a8;
    const float a32 = a16 * a16;
    const float ss = 0.04f;
    float al1 = powf(a1, (float)(lane + 1));
    float carry = 0.0f;
    int bi = wid / NF, f = wid - bi * NF;
    const float* pbase = Pp + (size_t)bi * TOUT * NF * 2 + f * 2;
    float* xrow = X + (size_t)wid * TOUT;
    float* mrow = M + (size_t)wid * TOUT;

    for (int c = 0; c < TOUT; c += 64) {
        int t = c + lane;
        float v = 0.0f;
        if (t < TOUT) {
            int s = t * 160 - 200;
            int cl = (s > 0) ? (s >> 9) : 0;          // first contributing tile
            int ch = (s + 400) >> 9;                  // last contributing tile
            if (ch > NCHUNKC - 1) ch = NCHUNKC - 1;
            v = pbase[(size_t)t * NF * 2 + (cl & 1)];
            if (ch > cl) v += pbase[(size_t)t * NF * 2 + ((cl & 1) ^ 1)];
            xrow[t] = v;
        }
        float y = ss * v;
        float u;
        u = __shfl_up(y, 1, 64);  if (lane >= 1)  y = fmaf(a1, u, y);
        u = __shfl_up(y, 2, 64);  if (lane >= 2)  y = fmaf(a2, u, y);
        u = __shfl_up(y, 4, 64);  if (lane >= 4)  y = fmaf(a4, u, y);
        u = __shfl_up(y, 8, 64);  if (lane >= 8)  y = fmaf(a8, u, y);
        u = __shfl_up(y, 16, 64); if (lane >= 16) y = fmaf(a16, u, y);
        u = __shfl_up(y, 32, 64); if (lane >= 32) y = fmaf(a32, u, y);
        y = fmaf(al1, carry, y);
        carry = __shfl(y, 63, 64);
        if (t < TOUT) mrow[t] = y;
    }
}

// ---------- GRU controller + PCEN via MFMA (C-layout gates); 8 instance-groups per block ----------
__global__ __launch_bounds__(256) void pcen_ctrl_mfma(
    const float* __restrict__ X, const float* __restrict__ M,
    const float* __restrict__ w_ih, const float* __restrict__ w_hh,
    const float* __restrict__ b_ih, const float* __restrict__ b_hh,
    const float* __restrict__ hw1, const float* __restrict__ hb1,
    const float* __restrict__ hw2, const float* __restrict__ hb2,
    float* __restrict__ out)
{
    __shared__ f16 s_whhA[96 * 40];
    __shared__ f16 s_w1A[32 * 40];
    __shared__ __align__(16) float4 s_A1[32];
    __shared__ __align__(16) float4 s_A2[32];
    __shared__ float s_hb1[32];
    __shared__ float s_hw2[64];
    __shared__ float s_hb2[2];
    __shared__ f16 sh1[4][16 * 40];
    __shared__ f16 sh2[4][16 * 40];
    __shared__ float sxc[4][16], sxp[4][16], smv[4][16];

    int tid = threadIdx.x;
    for (int i = tid; i < 96 * 32; i += 256) {
        int m = i >> 5, k = i & 31;
        s_whhA[m * 40 + k] = (f16)w_hh[i];
    }
    for (int i = tid; i < 32 * 32; i += 256) {
        int m = i >> 5, k = i & 31;
        s_w1A[m * 40 + k] = (f16)hw1[i];
    }
    if (tid < 32) {
        int j = tid;
        s_A1[j] = make_float4(w_ih[j], b_ih[j] + b_hh[j],
                              w_ih[32 + j], b_ih[32 + j] + b_hh[32 + j]);
        s_A2[j] = make_float4(w_ih[64 + j], b_ih[64 + j], b_hh[64 + j], 0.0f);
        s_hb1[j] = hb1[j];
    }
    if (tid < 64) s_hw2[tid] = hw2[tid];
    if (tid < 2)  s_hb2[tid] = hb2[tid];
    __syncthreads();

    int wv = tid >> 6, lane = tid & 63;
    int c = lane & 15, q = lane >> 4;

    for (int rep = 0; rep < 8; ++rep) {
        int instBase = blockIdx.x * 512 + rep * 64 + wv * 16;

        if (lane < 16) {
            int idx = instBase + lane;
            int t = idx % TOUT;
            float xcv = X[idx];
            float xpv = (t == 0) ? xcv : X[idx - 1];
            sxc[wv][lane] = xcv;
            sxp[wv][lane] = xpv;
            smv[wv][lane] = M[idx];
        }
        float xp = sxp[wv][c];
        float xc = sxc[wv][c];
        float mv = smv[wv][c];

        float h1v[8];
#pragma unroll
        for (int jj = 0; jj < 8; ++jj) {
            int j = (jj < 4) ? (4 * q + jj) : (16 + 4 * q + (jj - 4));
            float4 a1 = s_A1[j];
            float4 a2 = s_A2[j];
            float r = sigm(fmaf(xp, a1.x, a1.y));
            float z = sigm(fmaf(xp, a1.z, a1.w));
            float n = tanh_fast(fmaf(xp, a2.x, a2.y) + r * a2.z);
            h1v[jj] = (1.0f - z) * n;
        }

        {
            half4v lo = {(f16)h1v[0], (f16)h1v[1], (f16)h1v[2], (f16)h1v[3]};
            half4v hi = {(f16)h1v[4], (f16)h1v[5], (f16)h1v[6], (f16)h1v[7]};
            *(half4v*)(&sh1[wv][c * 40 + 4 * q]) = lo;
            *(half4v*)(&sh1[wv][c * 40 + 16 + 4 * q]) = hi;
        }

        float4v acc[6];
        {
            half8v bf = *(const half8v*)(&sh1[wv][c * 40 + 8 * q]);
#pragma unroll
            for (int t = 0; t < 6; ++t) {
                half8v af = *(const half8v*)(&s_whhA[(16 * t + c) * 40 + 8 * q]);
                acc[t] = __builtin_amdgcn_mfma_f32_16x16x32_f16(af, bf, (float4v){0.f,0.f,0.f,0.f}, 0, 0, 0);
            }
        }

        float h2v[8];
#pragma unroll
        for (int jj = 0; jj < 8; ++jj) {
            int j = (jj < 4) ? (4 * q + jj) : (16 + 4 * q + (jj - 4));
            int reg = jj & 3;
            float accR = (jj < 4) ? acc[0][reg] : acc[1][reg];
            float accZ = (jj < 4) ? acc[2][reg] : acc[3][reg];
            float accN = (jj < 4) ? acc[4][reg] : acc[5][reg];
            float4 a1 = s_A1[j];
            float4 a2 = s_A2[j];
            float r = sigm(fmaf(xc, a1.x, a1.y) + accR);
            float z = sigm(fmaf(xc, a1.z, a1.w) + accZ);
            float gn = accN + a2.z;
            float n = tanh_fast(fmaf(xc, a2.x, a2.y) + r * gn);
            h2v[jj] = fmaf(z, h1v[jj] - n, n);
        }

        {
            half4v lo = {(f16)h2v[0], (f16)h2v[1], (f16)h2v[2], (f16)h2v[3]};
            half4v hi = {(f16)h2v[4], (f16)h2v[5], (f16)h2v[6], (f16)h2v[7]};
            *(half4v*)(&sh2[wv][c * 40 + 4 * q]) = lo;
            *(half4v*)(&sh2[wv][c * 40 + 16 + 4 * q]) = hi;
        }

        float4v hacc[2];
        {
            half8v bf = *(const half8v*)(&sh2[wv][c * 40 + 8 * q]);
#pragma unroll
            for (int t = 0; t < 2; ++t) {
                half8v af = *(const half8v*)(&s_w1A[(16 * t + c) * 40 + 8 * q]);
                hacc[t] = __builtin_amdgcn_mfma_f32_16x16x32_f16(af, bf, (float4v){0.f,0.f,0.f,0.f}, 0, 0, 0);
            }
        }

        float p0 = 0.f, p1 = 0.f;
#pragma unroll
        for (int jj = 0; jj < 8; ++jj) {
            int i = (jj < 4) ? (4 * q + jj) : (16 + 4 * q + (jj - 4));
            int reg = jj & 3;
            float hv = (jj < 4) ? hacc[0][reg] : hacc[1][reg];
            hv = fmaxf(hv + s_hb1[i], 0.0f);
            p0 = fmaf(hv, s_hw2[i], p0);
            p1 = fmaf(hv, s_hw2[32 + i], p1);
        }
        p0 += __shfl_xor(p0, 16);
        p0 += __shfl_xor(p0, 32);
        p1 += __shfl_xor(p1, 16);
        p1 += __shfl_xor(p1, 32);

        float alpha = sigm(p0 + s_hb2[0]);
        float rr = fmaf(0.8f, sigm(p1 + s_hb2[1]), 0.2f);
        float md = __expf(alpha * __logf(mv + 1e-6f));
        float bse = xc / md + 2.0f;
        float val = __expf(rr * __logf(bse)) - __expf(rr * 0.69314718056f);
        if (lane < 16)
            out[instBase + lane] = val;
    }
}

extern "C" void kernel_launch(void* const* d_in, const int* in_sizes, int n_in,
                              void* d_out, int out_size, void* d_ws, size_t ws_size,
                              hipStream_t stream) {
    const float* x    = (const float*)d_in[0];
    const float* cf   = (const float*)d_in[1];
    const float* bw   = (const float*)d_in[2];
    const float* pw   = (const float*)d_in[3];
    const float* w_ih = (const float*)d_in[4];
    const float* w_hh = (const float*)d_in[5];
    const float* b_ih = (const float*)d_in[6];
    const float* b_hh = (const float*)d_in[7];
    const float* hw1  = (const float*)d_in[8];
    const float* hb1  = (const float*)d_in[9];
    const float* hw2  = (const float*)d_in[10];
    const float* hb2  = (const float*)d_in[11];
    float* out = (float*)d_out;

    // workspace: xb | Ag | Wf16 [40][WROW] f16 | Pp [BB][TOUT][NF][2] f32 | X | M  (~7.9 MB)
    f16* xb    = (f16*)d_ws;
    f16* Ag    = xb + (size_t)BB * LST;
    f16* Wf16  = Ag + (size_t)80 * AST;              // byte ofs 2,644,224 (16B aligned)
    float* Pp  = (float*)(Wf16 + (size_t)NF * WROW); // byte ofs 2,678,144 (16B aligned)
    float* Xf  = Pp + (size_t)BB * TOUT * NF * 2;
    float* Mf  = Xf + (size_t)BB * NF * TOUT;

    prep_all<<<dim3(NCONVB + 80 + 40), dim3(256), 0, stream>>>(
        x, cf, bw, pw, xb, Ag, Wf16);

    conv_pool<<<dim3(NCHUNKC, BB), dim3(256), 0, stream>>>(xb, Ag, Wf16, Pp);

    pcen_scan_kernel<<<dim3((BB * NF * 64) / 256), dim3(256), 0, stream>>>(Pp, Xf, Mf);
    pcen_ctrl_mfma<<<dim3((BB * NF * TOUT) / 512), dim3(256), 0, stream>>>(
        Xf, Mf, w_ih, w_hh, b_ih, b_hh, hw1, hb1, hw2, hb2, out);
}